// Round 5
// baseline (523.559 us; speedup 1.0000x reference)
//
#include <hip/hip_runtime.h>
#include <math.h>

// Reverse cumulative max (suffix max) along last dim.
// x: (8,1,2048,2048) fp32 -> 16384 rows of W=2048.
//
// R5 = R4 with the nontemporal-store type fixed (clang builtin requires a
// native vector type, not HIP_vector_type). Structure: each wave processes
// 4 rows (grid-stride), software-pipelined — row r+1's 8 global loads issue
// before row r's scan/store, keeping ~8KB outstanding per wave continuously
// (fix for the one-shot-wave structure that capped R1-R3 at 2.5 TB/s while
// fillBuffer hit 6.7 TB/s in the same replay). Register-direct layout (lane
// owns 32 contiguous floats — R3 proved coalescing irrelevant). No LDS, no
// barriers. Nontemporal stores keep write-once output out of L2/L3.

#define ROW_W 2048
#define BLOCKS 1024   // 1024 blocks x 4 waves = 4096 waves -> 4 rows/wave

typedef float nfloat4 __attribute__((ext_vector_type(4)));

__device__ __forceinline__ float max4(float4 a) {
  return fmaxf(fmaxf(a.x, a.y), fmaxf(a.z, a.w));
}

__global__ __launch_bounds__(256) void suffix_max_kernel(
    const float* __restrict__ x, float* __restrict__ out, int nrows) {
  const int wid  = (blockIdx.x * (blockDim.x >> 6)) + (threadIdx.x >> 6);
  const int lane = threadIdx.x & 63;
  const int nw   = gridDim.x * (blockDim.x >> 6);

  int row = wid;
  if (row >= nrows) return;

  float4 cur[8], nxt[8];
  {
    const float4* rp = (const float4*)(x + (size_t)row * ROW_W) + lane * 8;
#pragma unroll
    for (int k = 0; k < 8; ++k) cur[k] = rp[k];
  }

  while (row < nrows) {
    const int nrow = row + nw;
    // Prefetch next row BEFORE touching cur: these 8 loads stay in flight
    // through the entire scan below (compiler waits vmcnt(8), not vmcnt(0)).
    if (nrow < nrows) {
      const float4* rp = (const float4*)(x + (size_t)nrow * ROW_W) + lane * 8;
#pragma unroll
      for (int k = 0; k < 8; ++k) nxt[k] = rp[k];
    }

    // Lane max via depth-5 tree (independent of the serial chain below;
    // lets the shuffle chain start early).
    float t0 = fmaxf(max4(cur[0]), max4(cur[1]));
    float t1 = fmaxf(max4(cur[2]), max4(cur[3]));
    float t2 = fmaxf(max4(cur[4]), max4(cur[5]));
    float t3 = fmaxf(max4(cur[6]), max4(cur[7]));
    float m  = fmaxf(fmaxf(t0, t1), fmaxf(t2, t3));

    // Wave-wide inclusive suffix scan of lane maxes.
    float inc = m;
#pragma unroll
    for (int off = 1; off < 64; off <<= 1) {
      float o = __shfl_down(inc, off, 64);
      if (lane + off < 64) inc = fmaxf(inc, o);
    }
    float excl = __shfl_down(inc, 1, 64);
    if (lane == 63) excl = -INFINITY;

    // Serial suffix max over this lane's 32 floats (independent of the
    // shuffle chain until the fold).
    float run = -INFINITY;
#pragma unroll
    for (int k = 7; k >= 0; --k) {
      cur[k].w = fmaxf(cur[k].w, run);
      cur[k].z = fmaxf(cur[k].z, cur[k].w);
      cur[k].y = fmaxf(cur[k].y, cur[k].z);
      cur[k].x = fmaxf(cur[k].x, cur[k].y);
      run = cur[k].x;
    }

    // Fold in the right-neighbor suffix and store (nontemporal).
    nfloat4* wp = (nfloat4*)(out + (size_t)row * ROW_W) + lane * 8;
#pragma unroll
    for (int k = 0; k < 8; ++k) {
      nfloat4 v;
      v.x = fmaxf(cur[k].x, excl);
      v.y = fmaxf(cur[k].y, excl);
      v.z = fmaxf(cur[k].z, excl);
      v.w = fmaxf(cur[k].w, excl);
      __builtin_nontemporal_store(v, wp + k);
    }

    // Rotate pipeline.
#pragma unroll
    for (int k = 0; k < 8; ++k) cur[k] = nxt[k];
    row = nrow;
  }
}

extern "C" void kernel_launch(void* const* d_in, const int* in_sizes, int n_in,
                              void* d_out, int out_size, void* d_ws, size_t ws_size,
                              hipStream_t stream) {
  const float* x = (const float*)d_in[0];
  float* out = (float*)d_out;
  const int nrows = out_size / ROW_W;  // 16384
  suffix_max_kernel<<<BLOCKS, 256, 0, stream>>>(x, out, nrows);
}

// Round 6
// 250.353 us; speedup vs baseline: 2.0913x; 2.0913x over previous
//
#include <hip/hip_runtime.h>
#include <math.h>

// Reverse cumulative max (suffix max) along last dim.
// x: (8,1,2048,2048) fp32 -> 16384 rows of W=2048.
//
// R6 = R5 with PLAIN stores (NT stores caused 3x write amplification:
// 16B/lane partial-line fragments bypassed L2 write-merge -> WRITE_SIZE
// 128->374MB, BW 1.2 TB/s). This cleanly tests the multi-row pipeline:
// each wave processes 4 rows (grid-stride); row r+1's 8 global loads are
// issued before row r's scan/store so ~8KB stays outstanding per wave
// through the dependent scan tail (one-shot waves were the R1-R3 theory
// for 2.5 TB/s vs fillBuffer's 6.7 in the same replay). Register-direct
// layout (lane owns 32 contiguous floats); no LDS, no barriers.

#define ROW_W 2048
#define BLOCKS 1024   // 1024 blocks x 4 waves = 4096 waves -> 4 rows/wave

__device__ __forceinline__ float max4(float4 a) {
  return fmaxf(fmaxf(a.x, a.y), fmaxf(a.z, a.w));
}

__global__ __launch_bounds__(256) void suffix_max_kernel(
    const float* __restrict__ x, float* __restrict__ out, int nrows) {
  const int wid  = (blockIdx.x * (blockDim.x >> 6)) + (threadIdx.x >> 6);
  const int lane = threadIdx.x & 63;
  const int nw   = gridDim.x * (blockDim.x >> 6);

  int row = wid;
  if (row >= nrows) return;

  float4 cur[8], nxt[8];
  {
    const float4* rp = (const float4*)(x + (size_t)row * ROW_W) + lane * 8;
#pragma unroll
    for (int k = 0; k < 8; ++k) cur[k] = rp[k];
  }

  while (row < nrows) {
    const int nrow = row + nw;
    // Prefetch next row BEFORE touching cur: these 8 loads stay in flight
    // through the entire scan below (compiler waits vmcnt(8), not vmcnt(0)).
    if (nrow < nrows) {
      const float4* rp = (const float4*)(x + (size_t)nrow * ROW_W) + lane * 8;
#pragma unroll
      for (int k = 0; k < 8; ++k) nxt[k] = rp[k];
    }

    // Lane max via depth-5 tree (independent of the serial chain below;
    // lets the shuffle chain start early).
    float t0 = fmaxf(max4(cur[0]), max4(cur[1]));
    float t1 = fmaxf(max4(cur[2]), max4(cur[3]));
    float t2 = fmaxf(max4(cur[4]), max4(cur[5]));
    float t3 = fmaxf(max4(cur[6]), max4(cur[7]));
    float m  = fmaxf(fmaxf(t0, t1), fmaxf(t2, t3));

    // Wave-wide inclusive suffix scan of lane maxes.
    float inc = m;
#pragma unroll
    for (int off = 1; off < 64; off <<= 1) {
      float o = __shfl_down(inc, off, 64);
      if (lane + off < 64) inc = fmaxf(inc, o);
    }
    float excl = __shfl_down(inc, 1, 64);
    if (lane == 63) excl = -INFINITY;

    // Serial suffix max over this lane's 32 floats (independent of the
    // shuffle chain until the fold).
    float run = -INFINITY;
#pragma unroll
    for (int k = 7; k >= 0; --k) {
      cur[k].w = fmaxf(cur[k].w, run);
      cur[k].z = fmaxf(cur[k].z, cur[k].w);
      cur[k].y = fmaxf(cur[k].y, cur[k].z);
      cur[k].x = fmaxf(cur[k].x, cur[k].y);
      run = cur[k].x;
    }

    // Fold in the right-neighbor suffix and store (plain cached stores:
    // L2 merges the 16B/lane fragments into full lines before writeback).
    float4* wp = (float4*)(out + (size_t)row * ROW_W) + lane * 8;
#pragma unroll
    for (int k = 0; k < 8; ++k) {
      float4 v;
      v.x = fmaxf(cur[k].x, excl);
      v.y = fmaxf(cur[k].y, excl);
      v.z = fmaxf(cur[k].z, excl);
      v.w = fmaxf(cur[k].w, excl);
      wp[k] = v;
    }

    // Rotate pipeline.
#pragma unroll
    for (int k = 0; k < 8; ++k) cur[k] = nxt[k];
    row = nrow;
  }
}

extern "C" void kernel_launch(void* const* d_in, const int* in_sizes, int n_in,
                              void* d_out, int out_size, void* d_ws, size_t ws_size,
                              hipStream_t stream) {
  const float* x = (const float*)d_in[0];
  float* out = (float*)d_out;
  const int nrows = out_size / ROW_W;  // 16384
  suffix_max_kernel<<<BLOCKS, 256, 0, stream>>>(x, out, nrows);
}